// Round 3
// baseline (362.091 us; speedup 1.0000x reference)
//
#include <hip/hip_runtime.h>
#include <hip/hip_fp16.h>

#define N_NODES 100000
#define KK 5
#define CC 16
#define EE 3200000
#define NXCC 8

#define NB 16                // row buckets
#define ROWS_PB 6250         // N_NODES / NB
#define WCAP 512             // entries per (block,bucket) window: mean 320, +11 sigma
#define WPAD 513             // LDS stride: bucket bases land on distinct banks
#define BPB 64               // accum blocks per bucket (16*64 = 1024 blocks = 4/CU x 8 waves)
#define CHUNK 5120           // edges per scatter block
#define NCHUNK 3125          // 3125 * 5120 = 16,000,000
#define BLK_PER_K 625        // EE / CHUNK

__device__ __forceinline__ int xcc_id() {
    int x;
    asm volatile("s_getreg_b32 %0, hwreg(HW_REG_XCC_ID)" : "=s"(x));
    return x & (NXCC - 1);
}

// Kernel 1: Zt[k*N + n] = sum_c X[n,c] * h[c,k]
__global__ void compute_z_kernel(const float* __restrict__ X,
                                 const float* __restrict__ h,
                                 float* __restrict__ Zt) {
    int n = blockIdx.x * blockDim.x + threadIdx.x;
    if (n >= N_NODES) return;
    const float4* Xr = (const float4*)(X + (size_t)n * CC);
    float4 x0 = Xr[0], x1 = Xr[1], x2 = Xr[2], x3 = Xr[3];
    float xv[CC] = {x0.x, x0.y, x0.z, x0.w, x1.x, x1.y, x1.z, x1.w,
                    x2.x, x2.y, x2.z, x2.w, x3.x, x3.y, x3.z, x3.w};
#pragma unroll
    for (int k = 0; k < KK; ++k) {
        float acc = 0.0f;
#pragma unroll
        for (int c = 0; c < CC; ++c) acc += xv[c] * h[c * KK + k];
        Zt[k * N_NODES + n] = acc;
    }
}

// Phase A (R7): R5/R6 both sat at ~37% occupancy (~12 waves/CU) with waves
// parked on vmcnt -- compiler-visible MLP restructuring plateaued twice.
// This round: 512 threads/block (10 edges/thread: 2 int4-groups + 1 int2,
// since 16M = 2^10*5^6 has no 2048-multiple chunk), same 32.8 KB LDS
// -> 4 blocks x 8 waves = up to 32 waves/CU (2.7x measured concurrency).
__global__ __launch_bounds__(512, 2)
void scatter_kernel(const int* __restrict__ rows,
                    const int* __restrict__ cols,
                    const float* __restrict__ vals,
                    const float* __restrict__ Zt,
                    unsigned int* __restrict__ binned,
                    int* __restrict__ counts,
                    float* __restrict__ spill) {
    __shared__ int lcnt[NB];
    __shared__ unsigned int buf[NB * WPAD];           // 32.8 KB
    int tid = threadIdx.x;
    if (tid < NB) lcnt[tid] = 0;
    __syncthreads();

    int w = blockIdx.x;
    int cbase = w * CHUNK;
    const float* Zk = Zt + (size_t)(w / BLK_PER_K) * N_NODES;   // block shares one k

    // ---- phase 1: all inputs (9 vector loads in flight) ----
    int e0 = cbase + tid * 4;
    int e1 = cbase + 2048 + tid * 4;
    int e2 = cbase + 4096 + tid * 2;
    int4   r0 = *(const int4*)(rows + e0);
    int4   c0 = *(const int4*)(cols + e0);
    float4 v0 = *(const float4*)(vals + e0);
    int4   r1 = *(const int4*)(rows + e1);
    int4   c1 = *(const int4*)(cols + e1);
    float4 v1 = *(const float4*)(vals + e1);
    int2   r2 = *(const int2*)(rows + e2);
    int2   c2 = *(const int2*)(cols + e2);
    float2 v2 = *(const float2*)(vals + e2);

    // ---- phase 2: all 10 gathers issued before any consumer ----
    float z[10];
    z[0] = Zk[c0.x]; z[1] = Zk[c0.y]; z[2] = Zk[c0.z]; z[3] = Zk[c0.w];
    z[4] = Zk[c1.x]; z[5] = Zk[c1.y]; z[6] = Zk[c1.z]; z[7] = Zk[c1.w];
    z[8] = Zk[c2.x]; z[9] = Zk[c2.y];

    int   rr[10] = {r0.x, r0.y, r0.z, r0.w, r1.x, r1.y, r1.z, r1.w, r2.x, r2.y};
    float vv[10] = {v0.x, v0.y, v0.z, v0.w, v1.x, v1.y, v1.z, v1.w, v2.x, v2.y};

    // ---- phase 3: LDS position allocation, overlaps in-flight gathers ----
    int pos[10];
#pragma unroll
    for (int i = 0; i < 10; ++i) {
        int b = rr[i] / ROWS_PB;                      // compiler magic-mul
        pos[i] = atomicAdd(&lcnt[b], 1);
    }

    // ---- phase 4: pack + ds_write into staging buffer ----
#pragma unroll
    for (int i = 0; i < 10; ++i) {
        int b = rr[i] / ROWS_PB;
        float cb = vv[i] * z[i];
        int p = pos[i];
        if (p < WCAP) {
            unsigned int packed =
                ((unsigned)(rr[i] - b * ROWS_PB) << 16) |
                (unsigned)__half_as_ushort(__float2half_rn(cb));
            buf[b * WPAD + p] = packed;
        } else {
            unsafeAtomicAdd(&spill[rr[i]], cb);       // exact, ~never taken
        }
    }
    __syncthreads();

    // ---- phase 5: coalesced flush, bucket-major global layout [b][w][WCAP] --
    unsigned int* wbase = binned + (size_t)w * WCAP;
#pragma unroll 1
    for (int b = 0; b < NB; ++b) {
        int cnt = min(lcnt[b], WCAP);                 // wave-uniform (LDS bcast)
        unsigned int* dst = wbase + (size_t)b * ((size_t)NCHUNK * WCAP);
        if (tid < cnt) dst[tid] = buf[b * WPAD + tid];
    }
    if (tid < NB) counts[w * NB + tid] = min(lcnt[tid], WCAP);
}

// Phase B (R7): 512 threads (one full WCAP window per load instruction),
// BPB=64 -> 1024 blocks = exactly 4/CU x 8 waves = 32 waves/CU. Loads are
// PREDICATED again (R6's unpredicated variant over-read +38 MB of the
// binned stream); 8 windows unrolled -> 8 masked loads in flight.
__global__ __launch_bounds__(512, 2)
void accum_kernel(const unsigned int* __restrict__ binned,
                  const int* __restrict__ counts,
                  float* __restrict__ partials) {
    __shared__ float acc[ROWS_PB];                    // 25 KB
    __shared__ int cnts[56];                          // whi-wlo <= 49
    int b = blockIdx.x / BPB;
    int s = blockIdx.x % BPB;
    int tid = threadIdx.x;
    int wlo = (NCHUNK * s) / BPB;
    int whi = (NCHUNK * (s + 1)) / BPB;
    for (int i = tid; i < ROWS_PB; i += 512) acc[i] = 0.0f;
    if (tid < whi - wlo) cnts[tid] = counts[(wlo + tid) * NB + b];
    __syncthreads();

    const unsigned int* bbase = binned + (size_t)b * ((size_t)NCHUNK * WCAP);
    for (int w0 = wlo; w0 < whi; w0 += 8) {
        unsigned int e[8];
        int ok[8];
#pragma unroll
        for (int j = 0; j < 8; ++j) {
            int w = w0 + j;
            int cnt = (w < whi) ? cnts[w - wlo] : 0;
            ok[j] = tid < cnt;
            e[j]  = ok[j] ? bbase[(size_t)w * WCAP + tid] : 0u;
        }
#pragma unroll
        for (int j = 0; j < 8; ++j)
            if (ok[j])
                atomicAdd(&acc[e[j] >> 16],
                          __half2float(__ushort_as_half((unsigned short)(e[j] & 0xFFFFu))));
    }
    __syncthreads();
    float* dst = partials + (size_t)blockIdx.x * ROWS_PB;
    for (int i = tid; i < ROWS_PB; i += 512) dst[i] = acc[i];
}

// y[n] = spill[n] + sum over BPB partial slices of n's bucket
__global__ void reduce_kernel(const float* __restrict__ partials,
                              const float* __restrict__ spill,
                              float* __restrict__ y) {
    int n = blockIdx.x * blockDim.x + threadIdx.x;
    if (n >= N_NODES) return;
    int b = n / ROWS_PB, loc = n - b * ROWS_PB;
    const float* p = partials + (size_t)(b * BPB) * ROWS_PB + loc;
    float acc = spill[n];
#pragma unroll 8
    for (int s = 0; s < BPB; ++s) acc += p[(size_t)s * ROWS_PB];
    y[n] = acc;
}

// ---------- fallback path (R3): far-atomic scatter, used if ws too small ----
__global__ void edge_kernel_atomic(const int* __restrict__ rows,
                                   const int* __restrict__ cols,
                                   const float* __restrict__ vals,
                                   const float* __restrict__ Zt,
                                   float* __restrict__ yrep) {
    int t = blockIdx.x * blockDim.x + threadIdx.x;
    int base = t * 4;
    if (base >= KK * EE) return;
    int k = base / EE;
    const float* Zk = Zt + (size_t)k * N_NODES;
    float* y = yrep + (size_t)xcc_id() * N_NODES;
    int4 r = *(const int4*)(rows + base);
    int4 c = *(const int4*)(cols + base);
    float4 v = *(const float4*)(vals + base);
    unsafeAtomicAdd(&y[r.x], v.x * Zk[c.x]);
    unsafeAtomicAdd(&y[r.y], v.y * Zk[c.y]);
    unsafeAtomicAdd(&y[r.z], v.z * Zk[c.z]);
    unsafeAtomicAdd(&y[r.w], v.w * Zk[c.w]);
}

__global__ void reduce8_kernel(const float* __restrict__ yrep, float* __restrict__ y) {
    int n = blockIdx.x * blockDim.x + threadIdx.x;
    if (n >= N_NODES) return;
    float acc = 0.0f;
#pragma unroll
    for (int r = 0; r < NXCC; ++r) acc += yrep[(size_t)r * N_NODES + n];
    y[n] = acc;
}

extern "C" void kernel_launch(void* const* d_in, const int* in_sizes, int n_in,
                              void* d_out, int out_size, void* d_ws, size_t ws_size,
                              hipStream_t stream) {
    const float* X    = (const float*)d_in[0];
    const int*   rows = (const int*)  d_in[1];
    const int*   cols = (const int*)  d_in[2];
    const float* vals = (const float*)d_in[3];
    const float* h    = (const float*)d_in[4];
    float* y = (float*)d_out;

    char* ws = (char*)d_ws;
    float* Zt = (float*)ws;                                    //  2,000,000 B
    size_t counts_off  = 2000000;                              //    200,000 B
    size_t spill_off   = counts_off + 200000;                  //    400,000 B
    size_t binned_off  = spill_off + 400000;
    size_t binned_sz   = (size_t)NCHUNK * NB * WCAP * 4;       // 102,400,000 B
    size_t partial_off = binned_off + binned_sz;
    size_t partial_sz  = (size_t)NB * BPB * ROWS_PB * 4;       //  25,600,000 B
    size_t need = partial_off + partial_sz;                    // ~130.6 MB

    {   // Z = X @ h  (Zt layout [k][n])
        int threads = 256;
        int blocks  = (N_NODES + threads - 1) / threads;
        compute_z_kernel<<<blocks, threads, 0, stream>>>(X, h, Zt);
    }

    if (ws_size >= need) {
        int*          counts   = (int*)(ws + counts_off);
        float*        spill    = (float*)(ws + spill_off);
        unsigned int* binned   = (unsigned int*)(ws + binned_off);
        float*        partials = (float*)(ws + partial_off);
        hipMemsetAsync(spill, 0, 400000, stream);
        scatter_kernel<<<NCHUNK, 512, 0, stream>>>(rows, cols, vals, Zt,
                                                   binned, counts, spill);
        accum_kernel<<<NB * BPB, 512, 0, stream>>>(binned, counts, partials);
        {
            int threads = 256;
            int blocks  = (N_NODES + threads - 1) / threads;
            reduce_kernel<<<blocks, threads, 0, stream>>>(partials, spill, y);
        }
    } else {
        // fallback: R3 far-atomic path
        float* yrep = (float*)(ws + spill_off);
        hipMemsetAsync(yrep, 0, (size_t)NXCC * N_NODES * sizeof(float), stream);
        {
            int threads = 256;
            int blocks = ((KK * EE) / 4 + threads - 1) / threads;
            edge_kernel_atomic<<<blocks, threads, 0, stream>>>(rows, cols, vals, Zt, yrep);
        }
        {
            int threads = 256;
            int blocks  = (N_NODES + threads - 1) / threads;
            reduce8_kernel<<<blocks, threads, 0, stream>>>(yrep, y);
        }
    }
}

// Round 4
// 358.266 us; speedup vs baseline: 1.0107x; 1.0107x over previous
//
#include <hip/hip_runtime.h>
#include <hip/hip_fp16.h>

#define N_NODES 100000
#define KK 5
#define CC 16
#define EE 3200000
#define NXCC 8

#define NB 16                // row buckets
#define ROWS_PB 6250         // N_NODES / NB
#define WCAP 512             // entries per (block,bucket) window: mean 320, +11 sigma
#define WPAD 513             // LDS stride: bucket bases land on distinct banks
#define BPB 64               // accum blocks per bucket (16*64 = 1024 blocks)
#define CHUNK 5120           // edges per scatter block
#define NCHUNK 3125          // 3125 * 5120 = 16,000,000
#define BLK_PER_K 625        // EE / CHUNK

typedef unsigned int uint2v __attribute__((ext_vector_type(2)));

__device__ __forceinline__ int xcc_id() {
    int x;
    asm volatile("s_getreg_b32 %0, hwreg(HW_REG_XCC_ID)" : "=s"(x));
    return x & (NXCC - 1);
}

// Agent-scope relaxed load: emits sc0 -> bypasses the (non-coherent) per-CU L1,
// served from L2. Used for the random Zk gathers (zero L1 reuse: 400 KB slice
// through 32 KB L1 = pure thrash + MSHR occupancy).
__device__ __forceinline__ float ldg_l2(const float* p) {
    return __hip_atomic_load(p, __ATOMIC_RELAXED, __HIP_MEMORY_SCOPE_AGENT);
}

// Kernel 1: Zt[k*N + n] = sum_c X[n,c] * h[c,k]
__global__ void compute_z_kernel(const float* __restrict__ X,
                                 const float* __restrict__ h,
                                 float* __restrict__ Zt) {
    int n = blockIdx.x * blockDim.x + threadIdx.x;
    if (n >= N_NODES) return;
    const float4* Xr = (const float4*)(X + (size_t)n * CC);
    float4 x0 = Xr[0], x1 = Xr[1], x2 = Xr[2], x3 = Xr[3];
    float xv[CC] = {x0.x, x0.y, x0.z, x0.w, x1.x, x1.y, x1.z, x1.w,
                    x2.x, x2.y, x2.z, x2.w, x3.x, x3.y, x3.z, x3.w};
#pragma unroll
    for (int k = 0; k < KK; ++k) {
        float acc = 0.0f;
#pragma unroll
        for (int c = 0; c < CC; ++c) acc += xv[c] * h[c * KK + k];
        Zt[k * N_NODES + n] = acc;
    }
}

// Phase A (R8): R7 doubled occupancy (36->71%) with ZERO duration change ->
// scatter is throughput-walled in the divergent-gather path, not latency-
// bound. Hypothesis (a): L1 thrash/MSHR limit (400 KB Zk slice vs 32 KB L1,
// every miss holds an MSHR for the L2 round-trip). Test: agent-scope loads
// (sc0, L1 bypass) for the 10 gathers. If duration is unchanged the wall is
// TA lane-serialization (hypothesis b) -> col-binning rewrite next round.
__global__ __launch_bounds__(512, 2)
void scatter_kernel(const int* __restrict__ rows,
                    const int* __restrict__ cols,
                    const float* __restrict__ vals,
                    const float* __restrict__ Zt,
                    unsigned int* __restrict__ binned,
                    int* __restrict__ counts,
                    float* __restrict__ spill) {
    __shared__ int lcnt[NB];
    __shared__ unsigned int buf[NB * WPAD];           // 32.8 KB
    int tid = threadIdx.x;
    if (tid < NB) lcnt[tid] = 0;
    __syncthreads();

    int w = blockIdx.x;
    int cbase = w * CHUNK;
    const float* Zk = Zt + (size_t)(w / BLK_PER_K) * N_NODES;   // block shares one k

    // ---- phase 1: all inputs (9 vector loads in flight) ----
    int e0 = cbase + tid * 4;
    int e1 = cbase + 2048 + tid * 4;
    int e2 = cbase + 4096 + tid * 2;
    int4   r0 = *(const int4*)(rows + e0);
    int4   c0 = *(const int4*)(cols + e0);
    float4 v0 = *(const float4*)(vals + e0);
    int4   r1 = *(const int4*)(rows + e1);
    int4   c1 = *(const int4*)(cols + e1);
    float4 v1 = *(const float4*)(vals + e1);
    int2   r2 = *(const int2*)(rows + e2);
    int2   c2 = *(const int2*)(cols + e2);
    float2 v2 = *(const float2*)(vals + e2);

    // ---- phase 2: all 10 gathers, L1-bypassed, issued before any consumer --
    float z[10];
    z[0] = ldg_l2(&Zk[c0.x]); z[1] = ldg_l2(&Zk[c0.y]);
    z[2] = ldg_l2(&Zk[c0.z]); z[3] = ldg_l2(&Zk[c0.w]);
    z[4] = ldg_l2(&Zk[c1.x]); z[5] = ldg_l2(&Zk[c1.y]);
    z[6] = ldg_l2(&Zk[c1.z]); z[7] = ldg_l2(&Zk[c1.w]);
    z[8] = ldg_l2(&Zk[c2.x]); z[9] = ldg_l2(&Zk[c2.y]);

    int   rr[10] = {r0.x, r0.y, r0.z, r0.w, r1.x, r1.y, r1.z, r1.w, r2.x, r2.y};
    float vv[10] = {v0.x, v0.y, v0.z, v0.w, v1.x, v1.y, v1.z, v1.w, v2.x, v2.y};

    // ---- phase 3: LDS position allocation, overlaps in-flight gathers ----
    int pos[10];
#pragma unroll
    for (int i = 0; i < 10; ++i) {
        int b = rr[i] / ROWS_PB;                      // compiler magic-mul
        pos[i] = atomicAdd(&lcnt[b], 1);
    }

    // ---- phase 4: pack + ds_write into staging buffer ----
#pragma unroll
    for (int i = 0; i < 10; ++i) {
        int b = rr[i] / ROWS_PB;
        float cb = vv[i] * z[i];
        int p = pos[i];
        if (p < WCAP) {
            unsigned int packed =
                ((unsigned)(rr[i] - b * ROWS_PB) << 16) |
                (unsigned)__half_as_ushort(__float2half_rn(cb));
            buf[b * WPAD + p] = packed;
        } else {
            unsafeAtomicAdd(&spill[rr[i]], cb);       // exact, ~never taken
        }
    }
    __syncthreads();

    // ---- phase 5: coalesced flush, bucket-major global layout [b][w][WCAP] --
    unsigned int* wbase = binned + (size_t)w * WCAP;
#pragma unroll 1
    for (int b = 0; b < NB; ++b) {
        int cnt = min(lcnt[b], WCAP);                 // wave-uniform (LDS bcast)
        unsigned int* dst = wbase + (size_t)b * ((size_t)NCHUNK * WCAP);
        if (tid < cnt) dst[tid] = buf[b * WPAD + tid];
    }
    if (tid < NB) counts[w * NB + tid] = min(lcnt[tid], WCAP);
}

// Phase B (R8): accum is co-dominant (~130 us, always just under scatter).
// DS-atomic cost is ~2 us/CU and the stream is 64 MB (~10 us at BW) -> it is
// issue/MLP-limited. Restructure: uint2 payload (8 B/lane), two windows
// processed concurrently (tid split 2x256), 16 windows per outer iteration,
// 8 loads in flight -> half the iterations, double the payload per issue.
__global__ __launch_bounds__(512, 2)
void accum_kernel(const unsigned int* __restrict__ binned,
                  const int* __restrict__ counts,
                  float* __restrict__ partials) {
    __shared__ float acc[ROWS_PB];                    // 25 KB
    __shared__ int cnts[56];                          // whi-wlo <= 49
    int b = blockIdx.x / BPB;
    int s = blockIdx.x % BPB;
    int tid = threadIdx.x;
    int wlo = (NCHUNK * s) / BPB;
    int whi = (NCHUNK * (s + 1)) / BPB;
    for (int i = tid; i < ROWS_PB; i += 512) acc[i] = 0.0f;
    if (tid < whi - wlo) cnts[tid] = counts[(wlo + tid) * NB + b];
    __syncthreads();

    const unsigned int* bbase = binned + (size_t)b * ((size_t)NCHUNK * WCAP);
    int t    = tid & 255;                             // entry pair index
    int half = tid >> 8;                              // which window of the pair
    for (int w0 = wlo; w0 < whi; w0 += 16) {
        uint2v e[8];
        int ok0[8], ok1[8];
#pragma unroll
        for (int j = 0; j < 8; ++j) {
            int w = w0 + 2 * j + half;
            int cnt = (w < whi) ? cnts[w - wlo] : 0;
            ok0[j] = 2 * t < cnt;
            ok1[j] = 2 * t + 1 < cnt;
            const uint2v* src = (const uint2v*)(bbase + (size_t)w * WCAP);
            uint2v ez = {0u, 0u};
            e[j] = ok0[j] ? src[t] : ez;              // exec-masked 8B load
        }
#pragma unroll
        for (int j = 0; j < 8; ++j) {
            if (ok0[j])
                atomicAdd(&acc[e[j][0] >> 16],
                          __half2float(__ushort_as_half((unsigned short)(e[j][0] & 0xFFFFu))));
            if (ok1[j])
                atomicAdd(&acc[e[j][1] >> 16],
                          __half2float(__ushort_as_half((unsigned short)(e[j][1] & 0xFFFFu))));
        }
    }
    __syncthreads();
    float* dst = partials + (size_t)blockIdx.x * ROWS_PB;
    for (int i = tid; i < ROWS_PB; i += 512) dst[i] = acc[i];
}

// y[n] = spill[n] + sum over BPB partial slices of n's bucket
__global__ void reduce_kernel(const float* __restrict__ partials,
                              const float* __restrict__ spill,
                              float* __restrict__ y) {
    int n = blockIdx.x * blockDim.x + threadIdx.x;
    if (n >= N_NODES) return;
    int b = n / ROWS_PB, loc = n - b * ROWS_PB;
    const float* p = partials + (size_t)(b * BPB) * ROWS_PB + loc;
    float acc = spill[n];
#pragma unroll 8
    for (int s = 0; s < BPB; ++s) acc += p[(size_t)s * ROWS_PB];
    y[n] = acc;
}

// ---------- fallback path (R3): far-atomic scatter, used if ws too small ----
__global__ void edge_kernel_atomic(const int* __restrict__ rows,
                                   const int* __restrict__ cols,
                                   const float* __restrict__ vals,
                                   const float* __restrict__ Zt,
                                   float* __restrict__ yrep) {
    int t = blockIdx.x * blockDim.x + threadIdx.x;
    int base = t * 4;
    if (base >= KK * EE) return;
    int k = base / EE;
    const float* Zk = Zt + (size_t)k * N_NODES;
    float* y = yrep + (size_t)xcc_id() * N_NODES;
    int4 r = *(const int4*)(rows + base);
    int4 c = *(const int4*)(cols + base);
    float4 v = *(const float4*)(vals + base);
    unsafeAtomicAdd(&y[r.x], v.x * Zk[c.x]);
    unsafeAtomicAdd(&y[r.y], v.y * Zk[c.y]);
    unsafeAtomicAdd(&y[r.z], v.z * Zk[c.z]);
    unsafeAtomicAdd(&y[r.w], v.w * Zk[c.w]);
}

__global__ void reduce8_kernel(const float* __restrict__ yrep, float* __restrict__ y) {
    int n = blockIdx.x * blockDim.x + threadIdx.x;
    if (n >= N_NODES) return;
    float acc = 0.0f;
#pragma unroll
    for (int r = 0; r < NXCC; ++r) acc += yrep[(size_t)r * N_NODES + n];
    y[n] = acc;
}

extern "C" void kernel_launch(void* const* d_in, const int* in_sizes, int n_in,
                              void* d_out, int out_size, void* d_ws, size_t ws_size,
                              hipStream_t stream) {
    const float* X    = (const float*)d_in[0];
    const int*   rows = (const int*)  d_in[1];
    const int*   cols = (const int*)  d_in[2];
    const float* vals = (const float*)d_in[3];
    const float* h    = (const float*)d_in[4];
    float* y = (float*)d_out;

    char* ws = (char*)d_ws;
    float* Zt = (float*)ws;                                    //  2,000,000 B
    size_t counts_off  = 2000000;                              //    200,000 B
    size_t spill_off   = counts_off + 200000;                  //    400,000 B
    size_t binned_off  = spill_off + 400000;
    size_t binned_sz   = (size_t)NCHUNK * NB * WCAP * 4;       // 102,400,000 B
    size_t partial_off = binned_off + binned_sz;
    size_t partial_sz  = (size_t)NB * BPB * ROWS_PB * 4;       //  25,600,000 B
    size_t need = partial_off + partial_sz;                    // ~130.6 MB

    {   // Z = X @ h  (Zt layout [k][n])
        int threads = 256;
        int blocks  = (N_NODES + threads - 1) / threads;
        compute_z_kernel<<<blocks, threads, 0, stream>>>(X, h, Zt);
    }

    if (ws_size >= need) {
        int*          counts   = (int*)(ws + counts_off);
        float*        spill    = (float*)(ws + spill_off);
        unsigned int* binned   = (unsigned int*)(ws + binned_off);
        float*        partials = (float*)(ws + partial_off);
        hipMemsetAsync(spill, 0, 400000, stream);
        scatter_kernel<<<NCHUNK, 512, 0, stream>>>(rows, cols, vals, Zt,
                                                   binned, counts, spill);
        accum_kernel<<<NB * BPB, 512, 0, stream>>>(binned, counts, partials);
        {
            int threads = 256;
            int blocks  = (N_NODES + threads - 1) / threads;
            reduce_kernel<<<blocks, threads, 0, stream>>>(partials, spill, y);
        }
    } else {
        // fallback: R3 far-atomic path
        float* yrep = (float*)(ws + spill_off);
        hipMemsetAsync(yrep, 0, (size_t)NXCC * N_NODES * sizeof(float), stream);
        {
            int threads = 256;
            int blocks = ((KK * EE) / 4 + threads - 1) / threads;
            edge_kernel_atomic<<<blocks, threads, 0, stream>>>(rows, cols, vals, Zt, yrep);
        }
        {
            int threads = 256;
            int blocks  = (N_NODES + threads - 1) / threads;
            reduce8_kernel<<<blocks, threads, 0, stream>>>(yrep, y);
        }
    }
}

// Round 5
// 346.477 us; speedup vs baseline: 1.0451x; 1.0340x over previous
//
#include <hip/hip_runtime.h>
#include <hip/hip_fp16.h>

#define N_NODES 100000
#define KK 5
#define CC 16
#define EE 3200000
#define NXCC 8

#define NB 16                // row buckets
#define ROWS_PB 6250         // N_NODES / NB
#define WCAP 384             // entries per (chunk,bucket) window: mean 320, +3.7 sigma
                             // (~5 of 50k windows overflow -> exact spill path)
#define WPAD 385             // LDS stride: bucket bases land on distinct banks
#define BPB 64               // accum blocks per bucket (16*64 = 1024 blocks)
#define CHUNK 5120           // edges per scatter chunk
#define NCHUNK 3125          // 3125 * 5120 = 16,000,000
#define BLK_PER_K 625        // EE / CHUNK
#define SGRID 256            // persistent scatter blocks (1/CU)

typedef unsigned int uint2v __attribute__((ext_vector_type(2)));

__device__ __forceinline__ int xcc_id() {
    int x;
    asm volatile("s_getreg_b32 %0, hwreg(HW_REG_XCC_ID)" : "=s"(x));
    return x & (NXCC - 1);
}

// Kernel 1: Zt[k*N + n] (fp32, for fallback) and Zh[k*N + n] (fp16, for scatter)
__global__ void compute_z_kernel(const float* __restrict__ X,
                                 const float* __restrict__ h,
                                 float* __restrict__ Zt,
                                 __half* __restrict__ Zh) {
    int n = blockIdx.x * blockDim.x + threadIdx.x;
    if (n >= N_NODES) return;
    const float4* Xr = (const float4*)(X + (size_t)n * CC);
    float4 x0 = Xr[0], x1 = Xr[1], x2 = Xr[2], x3 = Xr[3];
    float xv[CC] = {x0.x, x0.y, x0.z, x0.w, x1.x, x1.y, x1.z, x1.w,
                    x2.x, x2.y, x2.z, x2.w, x3.x, x3.y, x3.z, x3.w};
#pragma unroll
    for (int k = 0; k < KK; ++k) {
        float acc = 0.0f;
#pragma unroll
        for (int c = 0; c < CC; ++c) acc += xv[c] * h[c * KK + k];
        Zt[k * N_NODES + n] = acc;
        Zh[k * N_NODES + n] = __float2half_rn(acc);
    }
}

// Phase A (R9): R3/R4 proved scatter sits at an L2 request-rate wall
// (~6.2 req/cyc/XCD, invariant under 2x occupancy and L1 bypass). The only
// fix is to NOT make the requests: cache the first SN nodes of Zk as fp16 in
// LDS (SN=65536 -> 128 KB covers 65.5% of uniform cols; residual 5.5M L2
// requests ~47us). Persistent blocks (grid=256, ~12 k-contiguous chunks each)
// load the slice ~once per block. Occupancy falls to 8 waves/CU -- safe,
// scatter is throughput-bound (R3: 2x waves = zero change).
// SN is template-selected at runtime via occupancy probe (SN=0 = no slice,
// ~R4 behavior) so an unlaunchable 153 KB LDS config degrades gracefully.
template<int SN>
__global__ __launch_bounds__(512, 2)
void scatter_lds_kernel(const int* __restrict__ rows,
                        const int* __restrict__ cols,
                        const float* __restrict__ vals,
                        const __half* __restrict__ Zh,
                        unsigned int* __restrict__ binned,
                        int* __restrict__ counts,
                        float* __restrict__ spill) {
    extern __shared__ char dynlds[];
    __half*       zsl = (__half*)dynlds;                   // SN*2 bytes
    unsigned int* buf = (unsigned int*)(dynlds + (size_t)SN * 2);  // NB*WPAD*4
    __shared__ int lcnt[NB];
    int tid = threadIdx.x;
    int bid = blockIdx.x;
    int w0 = (int)(((long long)NCHUNK * bid) / SGRID);
    int w1 = (int)(((long long)NCHUNK * (bid + 1)) / SGRID);

    int klast = -1;
    for (int w = w0; w < w1; ++w) {
        int k = w / BLK_PER_K;                             // block-uniform
        const __half* Zk_h = Zh + (size_t)k * N_NODES;
        if (SN > 0 && k != klast) {
            __syncthreads();                               // prior chunk done with zsl
            const float4* zsrc = (const float4*)Zk_h;      // 16B-aligned (k*200000 % 16 == 0)
            float4*       zdst = (float4*)dynlds;
#pragma unroll
            for (int i = 0; i < SN / 4096; ++i)            // SN/8 float4s, 512 thr
                zdst[tid + i * 512] = zsrc[tid + i * 512];
            klast = k;
            __syncthreads();
        }
        if (tid < NB) lcnt[tid] = 0;
        __syncthreads();

        int cbase = w * CHUNK;
        // ---- inputs: 9 vector loads in flight ----
        int e0 = cbase + tid * 4;
        int e1 = cbase + 2048 + tid * 4;
        int e2 = cbase + 4096 + tid * 2;
        int4   r0 = *(const int4*)(rows + e0);
        int4   c0 = *(const int4*)(cols + e0);
        float4 v0 = *(const float4*)(vals + e0);
        int4   r1 = *(const int4*)(rows + e1);
        int4   c1 = *(const int4*)(cols + e1);
        float4 v1 = *(const float4*)(vals + e1);
        int2   r2 = *(const int2*)(rows + e2);
        int2   c2 = *(const int2*)(cols + e2);
        float2 v2 = *(const float2*)(vals + e2);

        int   cc[10] = {c0.x, c0.y, c0.z, c0.w, c1.x, c1.y, c1.z, c1.w, c2.x, c2.y};
        int   rr[10] = {r0.x, r0.y, r0.z, r0.w, r1.x, r1.y, r1.z, r1.w, r2.x, r2.y};
        float vv[10] = {v0.x, v0.y, v0.z, v0.w, v1.x, v1.y, v1.z, v1.w, v2.x, v2.y};

        // ---- gathers: LDS slice hit (~65%) or residual L2 request ----
        float z[10];
#pragma unroll
        for (int i = 0; i < 10; ++i) {
            unsigned c = (unsigned)cc[i];
            __half hz;
            if (SN > 0 && c < (unsigned)SN) hz = zsl[c];
            else                            hz = Zk_h[c];
            z[i] = __half2float(hz);
        }

        // ---- LDS position allocation (overlaps residual gathers) ----
        int pos[10];
#pragma unroll
        for (int i = 0; i < 10; ++i) {
            int b = rr[i] / ROWS_PB;                       // magic-mul
            pos[i] = atomicAdd(&lcnt[b], 1);
        }

        // ---- pack + stage ----
#pragma unroll
        for (int i = 0; i < 10; ++i) {
            int b = rr[i] / ROWS_PB;
            float cb = vv[i] * z[i];
            int p = pos[i];
            if (p < WCAP) {
                unsigned int packed =
                    ((unsigned)(rr[i] - b * ROWS_PB) << 16) |
                    (unsigned)__half_as_ushort(__float2half_rn(cb));
                buf[b * WPAD + p] = packed;
            } else {
                unsafeAtomicAdd(&spill[rr[i]], cb);        // exact, ~never taken
            }
        }
        __syncthreads();

        // ---- coalesced flush, bucket-major global layout [b][w][WCAP] ----
        unsigned int* wbase = binned + (size_t)w * WCAP;
#pragma unroll 1
        for (int b = 0; b < NB; ++b) {
            int cnt = min(lcnt[b], WCAP);                  // wave-uniform
            if (tid < cnt)
                wbase[(size_t)b * ((size_t)NCHUNK * WCAP) + tid] = buf[b * WPAD + tid];
        }
        if (tid < NB) counts[w * NB + tid] = min(lcnt[tid], WCAP);
        __syncthreads();                                   // buf/lcnt reuse next chunk
    }
}

// Phase B: counts in LDS; uint2 payload, two windows concurrent (tid split
// 2x256), 16 windows/outer iter, 8 predicated loads in flight -> ds_add burst.
__global__ __launch_bounds__(512, 2)
void accum_kernel(const unsigned int* __restrict__ binned,
                  const int* __restrict__ counts,
                  float* __restrict__ partials) {
    __shared__ float acc[ROWS_PB];                    // 25 KB
    __shared__ int cnts[56];                          // whi-wlo <= 49
    int b = blockIdx.x / BPB;
    int s = blockIdx.x % BPB;
    int tid = threadIdx.x;
    int wlo = (NCHUNK * s) / BPB;
    int whi = (NCHUNK * (s + 1)) / BPB;
    for (int i = tid; i < ROWS_PB; i += 512) acc[i] = 0.0f;
    if (tid < whi - wlo) cnts[tid] = counts[(wlo + tid) * NB + b];
    __syncthreads();

    const unsigned int* bbase = binned + (size_t)b * ((size_t)NCHUNK * WCAP);
    int t    = tid & 255;                             // entry-pair index
    int half = tid >> 8;                              // which window of the pair
    for (int w0 = wlo; w0 < whi; w0 += 16) {
        uint2v e[8];
        int ok0[8], ok1[8];
#pragma unroll
        for (int j = 0; j < 8; ++j) {
            int w = w0 + 2 * j + half;
            int cnt = (w < whi) ? cnts[w - wlo] : 0;
            ok0[j] = 2 * t < cnt;
            ok1[j] = 2 * t + 1 < cnt;
            const uint2v* src = (const uint2v*)(bbase + (size_t)w * WCAP);
            uint2v ez = {0u, 0u};
            e[j] = ok0[j] ? src[t] : ez;              // exec-masked 8B load
        }
#pragma unroll
        for (int j = 0; j < 8; ++j) {
            if (ok0[j])
                atomicAdd(&acc[e[j][0] >> 16],
                          __half2float(__ushort_as_half((unsigned short)(e[j][0] & 0xFFFFu))));
            if (ok1[j])
                atomicAdd(&acc[e[j][1] >> 16],
                          __half2float(__ushort_as_half((unsigned short)(e[j][1] & 0xFFFFu))));
        }
    }
    __syncthreads();
    float* dst = partials + (size_t)blockIdx.x * ROWS_PB;
    for (int i = tid; i < ROWS_PB; i += 512) dst[i] = acc[i];
}

// y[n] = spill[n] + sum over BPB partial slices of n's bucket
__global__ void reduce_kernel(const float* __restrict__ partials,
                              const float* __restrict__ spill,
                              float* __restrict__ y) {
    int n = blockIdx.x * blockDim.x + threadIdx.x;
    if (n >= N_NODES) return;
    int b = n / ROWS_PB, loc = n - b * ROWS_PB;
    const float* p = partials + (size_t)(b * BPB) * ROWS_PB + loc;
    float acc = spill[n];
#pragma unroll 8
    for (int s = 0; s < BPB; ++s) acc += p[(size_t)s * ROWS_PB];
    y[n] = acc;
}

// ---------- fallback path: far-atomic scatter, used if ws too small ----
__global__ void edge_kernel_atomic(const int* __restrict__ rows,
                                   const int* __restrict__ cols,
                                   const float* __restrict__ vals,
                                   const float* __restrict__ Zt,
                                   float* __restrict__ yrep) {
    int t = blockIdx.x * blockDim.x + threadIdx.x;
    int base = t * 4;
    if (base >= KK * EE) return;
    int k = base / EE;
    const float* Zk = Zt + (size_t)k * N_NODES;
    float* y = yrep + (size_t)xcc_id() * N_NODES;
    int4 r = *(const int4*)(rows + base);
    int4 c = *(const int4*)(cols + base);
    float4 v = *(const float4*)(vals + base);
    unsafeAtomicAdd(&y[r.x], v.x * Zk[c.x]);
    unsafeAtomicAdd(&y[r.y], v.y * Zk[c.y]);
    unsafeAtomicAdd(&y[r.z], v.z * Zk[c.z]);
    unsafeAtomicAdd(&y[r.w], v.w * Zk[c.w]);
}

__global__ void reduce8_kernel(const float* __restrict__ yrep, float* __restrict__ y) {
    int n = blockIdx.x * blockDim.x + threadIdx.x;
    if (n >= N_NODES) return;
    float acc = 0.0f;
#pragma unroll
    for (int r = 0; r < NXCC; ++r) acc += yrep[(size_t)r * N_NODES + n];
    y[n] = acc;
}

extern "C" void kernel_launch(void* const* d_in, const int* in_sizes, int n_in,
                              void* d_out, int out_size, void* d_ws, size_t ws_size,
                              hipStream_t stream) {
    const float* X    = (const float*)d_in[0];
    const int*   rows = (const int*)  d_in[1];
    const int*   cols = (const int*)  d_in[2];
    const float* vals = (const float*)d_in[3];
    const float* h    = (const float*)d_in[4];
    float* y = (float*)d_out;

    char* ws = (char*)d_ws;
    float*  Zt = (float*)ws;                                   //  2,000,000 B
    size_t zh_off      = 2000000;                              //  1,000,000 B
    size_t counts_off  = 3000000;                              //    200,000 B
    size_t spill_off   = 3200000;                              //    400,000 B
    size_t binned_off  = 3600000;
    size_t binned_sz   = (size_t)NCHUNK * NB * WCAP * 4;       //  76,800,000 B
    size_t partial_off = binned_off + binned_sz;
    size_t partial_sz  = (size_t)NB * BPB * ROWS_PB * 4;       //  25,600,000 B
    size_t need = partial_off + partial_sz;                    // ~106.0 MB
    __half* Zh = (__half*)(ws + zh_off);

    {   // Z = X @ h  (Zt layout [k][n], fp32 + fp16)
        int threads = 256;
        int blocks  = (N_NODES + threads - 1) / threads;
        compute_z_kernel<<<blocks, threads, 0, stream>>>(X, h, Zt, Zh);
    }

    if (ws_size >= need) {
        int*          counts   = (int*)(ws + counts_off);
        float*        spill    = (float*)(ws + spill_off);
        unsigned int* binned   = (unsigned int*)(ws + binned_off);
        float*        partials = (float*)(ws + partial_off);
        hipMemsetAsync(spill, 0, 400000, stream);

        // runtime probe: largest launchable Z-slice (capture-legal queries only)
        static int g_sn = -1;
        const size_t stag = (size_t)NB * WPAD * 4;             // 24,640 B
        if (g_sn < 0) {
            g_sn = 0;
            int nb = 0;
            hipFuncSetAttribute((const void*)scatter_lds_kernel<65536>,
                                hipFuncAttributeMaxDynamicSharedMemorySize,
                                (int)(65536 * 2 + stag));
            if (hipOccupancyMaxActiveBlocksPerMultiprocessor(
                    &nb, scatter_lds_kernel<65536>, 512, 65536 * 2 + stag) == hipSuccess
                && nb >= 1) g_sn = 65536;
            if (g_sn == 0) {
                nb = 0;
                hipFuncSetAttribute((const void*)scatter_lds_kernel<49152>,
                                    hipFuncAttributeMaxDynamicSharedMemorySize,
                                    (int)(49152 * 2 + stag));
                if (hipOccupancyMaxActiveBlocksPerMultiprocessor(
                        &nb, scatter_lds_kernel<49152>, 512, 49152 * 2 + stag) == hipSuccess
                    && nb >= 1) g_sn = 49152;
            }
            if (g_sn == 0) {
                nb = 0;
                hipFuncSetAttribute((const void*)scatter_lds_kernel<32768>,
                                    hipFuncAttributeMaxDynamicSharedMemorySize,
                                    (int)(32768 * 2 + stag));
                if (hipOccupancyMaxActiveBlocksPerMultiprocessor(
                        &nb, scatter_lds_kernel<32768>, 512, 32768 * 2 + stag) == hipSuccess
                    && nb >= 1) g_sn = 32768;
            }
        }
        size_t dyn = (size_t)g_sn * 2 + stag;
        switch (g_sn) {
        case 65536:
            scatter_lds_kernel<65536><<<SGRID, 512, dyn, stream>>>(
                rows, cols, vals, Zh, binned, counts, spill);
            break;
        case 49152:
            scatter_lds_kernel<49152><<<SGRID, 512, dyn, stream>>>(
                rows, cols, vals, Zh, binned, counts, spill);
            break;
        case 32768:
            scatter_lds_kernel<32768><<<SGRID, 512, dyn, stream>>>(
                rows, cols, vals, Zh, binned, counts, spill);
            break;
        default:
            scatter_lds_kernel<0><<<SGRID, 512, dyn, stream>>>(
                rows, cols, vals, Zh, binned, counts, spill);
            break;
        }

        accum_kernel<<<NB * BPB, 512, 0, stream>>>(binned, counts, partials);
        {
            int threads = 256;
            int blocks  = (N_NODES + threads - 1) / threads;
            reduce_kernel<<<blocks, threads, 0, stream>>>(partials, spill, y);
        }
    } else {
        // fallback: far-atomic path
        float* yrep = (float*)(ws + spill_off);
        hipMemsetAsync(yrep, 0, (size_t)NXCC * N_NODES * sizeof(float), stream);
        {
            int threads = 256;
            int blocks = ((KK * EE) / 4 + threads - 1) / threads;
            edge_kernel_atomic<<<blocks, threads, 0, stream>>>(rows, cols, vals, Zt, yrep);
        }
        {
            int threads = 256;
            int blocks  = (N_NODES + threads - 1) / threads;
            reduce8_kernel<<<blocks, threads, 0, stream>>>(yrep, y);
        }
    }
}